// Round 4
// baseline (759.006 us; speedup 1.0000x reference)
//
// AttLayer block-local attention, MI355X gfx950.
// R4: fix R3's cross-wave RAW race. vmcnt is PER-WAVE: a wave's VM(8) says
//     nothing about other waves' staging loads, and LDS units are staged
//     collectively. Every VM(8) now sits at the END of the prior phase,
//     before the trailing s_barrier (VM -> SBAR -> dependent ds_reads), so
//     the per-wave certification becomes block-wide. Counts unchanged
//     (no gloads issue between old and new positions). One barrier/phase.
//   Re-verified hazard tables (cross-wave):
//     RAW gload->ds_read : end-of-phase VM(8)+SBAR covers exactly the unit
//       the next phase reads (prologue->b0.012, P0->b0.3, P2->b1.01,
//       P3->b1.2, P4->b1.3, P6->b0'.01, P7->b0'.2)
//     WAR ds_read->gload : every region has >=2-phase read->restage gap;
//       reads certified by reader's LGKM before an intervening SBAR
//     reg lifetimes      : fa03 P3..P5 ow P7 | fa47 P5..P7 ow P1 |
//                          fb01 P3..P6 ow P7 | fb23 P4..P7 ow P0  (b1 half)
// Workspace: xT | Wqk | Wv | Wo | qkT | v | S | P | guard (attT aliases xT).

#include <hip/hip_runtime.h>
#include <hip/hip_bf16.h>

typedef __attribute__((ext_vector_type(4))) float f32x4;
typedef __attribute__((ext_vector_type(8))) __bf16 bf16x8;

#define DEVINL static __device__ __forceinline__

DEVINL unsigned short f2bf(float f) {  // RTNE float->bf16
  union { float f; unsigned u; } x; x.f = f;
  return (unsigned short)((x.u + 0x7FFFu + ((x.u >> 16) & 1u)) >> 16);
}

DEVINL void gload16(const void* g, void* l) {
  __builtin_amdgcn_global_load_lds((const __attribute__((address_space(1))) void*)g,
                                   (__attribute__((address_space(3))) void*)l,
                                   16, 0, 0);
}

#define SBAR()   asm volatile("s_barrier" ::: "memory")
#define LGKM(n)  asm volatile("s_waitcnt lgkmcnt(" #n ")" ::: "memory")
#define VM(n)    asm volatile("s_waitcnt vmcnt(" #n ")" ::: "memory")
#define SCHED0() __builtin_amdgcn_sched_barrier(0)

// ---------------------------------------------------------------- transpose x
__global__ __launch_bounds__(256) void transpose_x_k(const float* __restrict__ x,
                                                     unsigned short* __restrict__ xT) {
  __shared__ float tile[32][33];
  const int bx = blockIdx.x;  // 512
  const int by = blockIdx.y;  // 64
  const int tx = threadIdx.x; // 32
  const int ty = threadIdx.y; // 8
#pragma unroll
  for (int i = 0; i < 4; ++i) {
    int c = by * 32 + ty + i * 8;
    tile[ty + i * 8][tx] = x[(long)c * 16384 + bx * 32 + tx];
  }
  __syncthreads();
#pragma unroll
  for (int i = 0; i < 4; ++i) {
    int l = bx * 32 + ty + i * 8;
    xT[(long)l * 2048 + by * 32 + tx] = f2bf(tile[tx][ty + i * 8]);
  }
}

// ------------------------------------------------------------ weight convert
__global__ __launch_bounds__(256) void conv_w_k(const float* __restrict__ wq,
                                                const float* __restrict__ wk,
                                                const float* __restrict__ wv,
                                                const float* __restrict__ wo,
                                                unsigned short* __restrict__ Wqk,
                                                unsigned short* __restrict__ Wv,
                                                unsigned short* __restrict__ Wo) {
  long i = (long)blockIdx.x * 256 + threadIdx.x;
  if (i < 4194304) {
    float s = (i < 2097152) ? wq[i] : wk[i - 2097152];
    Wqk[i] = f2bf(s);
  } else if (i < 6291456) {
    Wv[i - 4194304] = f2bf(wv[i - 4194304]);
  } else {
    Wo[i - 6291456] = f2bf(wo[i - 6291456]);
  }
}

// ------------------------------------------------------------------ GEMM core
enum { EPI_QK = 0, EPI_V = 1, EPI_S = 2, EPI_PV = 3, EPI_OUT = 4 };

struct GArgs {
  const unsigned short* A;
  const unsigned short* Bt;
  void* C;
  const float* bias;
  const float* bias2;
  const float* mask;
  const unsigned short* guard;
  int aBatch, cBatch;
  int btRow0, btRow0Step, btRowLim;
  int btK0, btK0Step, btKLim;
};

// 256x256 tile, BK=64, 8 waves (2M x 4N), per-wave 128x64, phase-prefetched.
template <int EPI, int LDA, int LDB, int LDC, int KK>
__global__ __launch_bounds__(512, 2) void gemm8_k(GArgs g) {
  constexpr int NK = KK >> 6;
  constexpr int NT = NK >> 1;
  __shared__ char lds[131072];

  const int t = threadIdx.x;
  const int l = t & 63;
  const int w = t >> 6;

  // XCD chunk swizzle (all grids % 8 == 0): each XCD gets a contiguous chunk.
  const int gx = gridDim.x, gxy = gx * gridDim.y;
  const int nwg = gxy * gridDim.z;
  int lin = blockIdx.z * gxy + blockIdx.y * gx + blockIdx.x;
  lin = (lin & 7) * (nwg >> 3) + (lin >> 3);
  const int z = lin / gxy;
  const int rres = lin - z * gxy;
  const int Mbase = (rres / gx) << 8;
  const int Nbase = (rres - (rres / gx) * gx) << 8;

  const int wr = w >> 2;
  const int wc = w & 3;
  const int fr = l & 15;
  const int fg = l >> 4;

  const unsigned short* Ab = g.A + (long)z * g.aBatch + (long)Mbase * LDA;
  const int bRowBase = g.btRow0 + z * g.btRow0Step + Nbase;
  const int bK0 = g.btK0 + z * g.btK0Step;

  const int rr = t >> 3;
  const int cb8s = t & 7;

  // stage one 16 KiB unit (2 gloads/thread) of K-tile kt into buf.
  // unit 0: A rows 0-63,128-191   unit 3: A rows 64-127,192-255
  // unit 1: B rows {0-31,64-95},{128-159,192-223}
  // unit 2: B rows {32-63,96-127},{160-191,224-255}
  auto stage = [&](int bufSel, int unit, int kt) {
    const int k0 = (kt & (NK - 1)) << 6;
    const bool isA = (unit == 0) || (unit == 3);
#pragma unroll
    for (int gph = 0; gph < 2; ++gph) {
      int row;
      if (isA) row = (unit == 0 ? 0 : 64) + (gph << 7) + rr;
      else     row = (unit == 1 ? 0 : 32) + (gph << 7) + (rr & 31) + ((rr >> 5) << 6);
      const int cbL = cb8s ^ (row & 7);
      const int gk = k0 + (cbL << 3);
      char* lp = lds + (bufSel << 16) + (isA ? 0 : 32768) + row * 128 + (cb8s << 4);
      const char* gp;
      if (isA) {
        gp = (const char*)(Ab + (long)row * LDA + gk);
      } else {
        const int grow = bRowBase + row;
        const int gkk = bK0 + gk;
        if ((unsigned)grow < (unsigned)g.btRowLim && (unsigned)gkk < (unsigned)g.btKLim)
          gp = (const char*)(g.Bt + (long)grow * LDB + gkk);
        else
          gp = (const char*)g.guard + (l << 4);
      }
      gload16(gp, lp);
    }
  };

  const int arow = (wr << 7) + fr;
  const int brow = (wc << 6) + fr;

  auto ldA = [&](int i8, int kk, int bufSel) -> bf16x8 {
    const int row = arow + (i8 << 4);
    const int cb = ((kk << 2) | fg) ^ (row & 7);
    return *(const bf16x8*)(lds + (bufSel << 16) + row * 128 + (cb << 4));
  };
  auto ldB = [&](int j, int kk, int bufSel) -> bf16x8 {
    const int row = brow + (j << 4);
    const int cb = ((kk << 2) | fg) ^ (row & 7);
    return *(const bf16x8*)(lds + (bufSel << 16) + 32768 + row * 128 + (cb << 4));
  };

  f32x4 acc[8][4];
#pragma unroll
  for (int i = 0; i < 8; ++i)
#pragma unroll
    for (int j = 0; j < 4; ++j) acc[i][j] = f32x4{0.f, 0.f, 0.f, 0.f};

  bf16x8 fa[8][2], fb[4][2];

#define RD_FA03(b) _Pragma("unroll") for (int i = 0; i < 4; ++i) { fa[i][0] = ldA(i, 0, b); fa[i][1] = ldA(i, 1, b); }
#define RD_FA47(b) _Pragma("unroll") for (int i = 4; i < 8; ++i) { fa[i][0] = ldA(i, 0, b); fa[i][1] = ldA(i, 1, b); }
#define RD_FB01(b) _Pragma("unroll") for (int j = 0; j < 2; ++j) { fb[j][0] = ldB(j, 0, b); fb[j][1] = ldB(j, 1, b); }
#define RD_FB23(b) _Pragma("unroll") for (int j = 2; j < 4; ++j) { fb[j][0] = ldB(j, 0, b); fb[j][1] = ldB(j, 1, b); }

#define MQ(I0, J0)                                                            \
  __builtin_amdgcn_s_setprio(1);                                              \
  _Pragma("unroll") for (int i = 0; i < 4; ++i)                               \
  _Pragma("unroll") for (int j = 0; j < 2; ++j)                               \
  _Pragma("unroll") for (int kk = 0; kk < 2; ++kk)                            \
    acc[(I0) + i][(J0) + j] = __builtin_amdgcn_mfma_f32_16x16x32_bf16(        \
        fa[(I0) + i][kk], fb[(J0) + j][kk], acc[(I0) + i][(J0) + j], 0, 0, 0);\
  __builtin_amdgcn_s_setprio(0);

  // prologue: buf0 fully (kt0), buf1 units 0-2 (kt1). 14 gloads in flight.
  stage(0, 0, 0); stage(0, 1, 0); stage(0, 2, 0); stage(0, 3, 0);
  stage(1, 0, 1); stage(1, 1, 1); stage(1, 2, 1);
  VM(8);                  // own b0.{0,1,2} landed
  SBAR();                 // -> block-wide: all waves' b0.{0,1,2} landed
  RD_FA03(0); RD_FB01(0); // fragments for P0 (12 ds_reads)

#pragma unroll 1
  for (int it = 0; it < NT; ++it) {
    const int kt1 = 2 * it + 1;
    const int ktn0 = 2 * it + 2;
    const int ktn1 = 2 * it + 3;
    // P0: MQ Q00(b0); prefetch fb23(b0); end-VM certifies b0.3 for P1
    RD_FB23(0); stage(1, 3, kt1);
    LGKM(4); SCHED0();
    MQ(0, 0);
    VM(8); SBAR();
    // P1: MQ Q01(b0); prefetch fa47(b0); P2 reads nothing -> no VM
    RD_FA47(0); stage(0, 0, ktn0);
    LGKM(8); SCHED0();
    MQ(0, 2);
    SBAR();
    // P2: MQ Q10(b0); end-VM certifies b1.{0,1} for P3
    stage(0, 1, ktn0);
    LGKM(0); SCHED0();
    MQ(4, 0);
    VM(8); SBAR();
    // P3: MQ Q11(b0); prefetch fa03,fb01(b1); end-VM certifies b1.2 for P4
    RD_FA03(1); RD_FB01(1); stage(0, 2, ktn0);
    LGKM(12); SCHED0();
    MQ(4, 2);
    VM(8); SBAR();
    // P4: MQ Q00(b1); prefetch fb23(b1); end-VM certifies b1.3 for P5
    RD_FB23(1); stage(0, 3, ktn0);
    LGKM(4); SCHED0();
    MQ(0, 0);
    VM(8); SBAR();
    // P5: MQ Q01(b1); prefetch fa47(b1); P6 reads nothing -> no VM
    RD_FA47(1); stage(1, 0, ktn1);
    LGKM(8); SCHED0();
    MQ(0, 2);
    SBAR();
    // P6: MQ Q10(b1); end-VM certifies b0'.{0,1} for P7
    stage(1, 1, ktn1);
    LGKM(0); SCHED0();
    MQ(4, 0);
    VM(8); SBAR();
    // P7: MQ Q11(b1); prefetch fa03,fb01(b0'); end-VM certifies b0'.2 for P0
    RD_FA03(0); RD_FB01(0); stage(1, 2, ktn1);
    LGKM(12); SCHED0();
    MQ(4, 2);
    VM(8); SBAR();
  }
  VM(0); LGKM(0); SBAR();  // drain wrapped prefetches before epilogue

  // epilogue: D row=(lane>>4)*4+r, col=lane&15 within each 16x16 fragment
#pragma unroll
  for (int ii = 0; ii < 8; ++ii)
#pragma unroll
    for (int j = 0; j < 4; ++j)
#pragma unroll
      for (int r = 0; r < 4; ++r) {
        const int row = Mbase + (wr << 7) + ii * 16 + fg * 4 + r;
        const int col = Nbase + (wc << 6) + j * 16 + fr;
        float val = acc[ii][j][r];
        const long off = (long)z * g.cBatch + (long)row * LDC + col;
        if (EPI == EPI_QK) {
          val = (col < 1024) ? (val + g.bias[col]) * 0.03125f
                             : (val + g.bias2[col - 1024]);
          ((unsigned short*)g.C)[off] = f2bf(val);
        } else if (EPI == EPI_V) {
          val += g.bias[row];
          ((unsigned short*)g.C)[off] = f2bf(val);
        } else if (EPI == EPI_S) {
          ((float*)g.C)[off] = val;
        } else if (EPI == EPI_PV) {
          val = fmaxf(val, 0.f);
          ((unsigned short*)g.C)[off] = f2bf(val);
        } else {
          val = (val + g.bias[row]) * g.mask[col];
          ((float*)g.C)[off] = val;
        }
      }
#undef MQ
#undef RD_FA03
#undef RD_FA47
#undef RD_FB01
#undef RD_FB23
}

// ------------------------------------------------------------------- softmax
__global__ __launch_bounds__(256) void softmax_k(const float* __restrict__ S,
                                                 const float* __restrict__ mask,
                                                 unsigned short* __restrict__ P) {
  const int row = blockIdx.x;
  const int n = row >> 9;
  const float* s = S + (long)row * 1024;
  unsigned short* p = P + (long)row * 1024;
  const int t = threadIdx.x;

  float logit[4], fm[4];
  float lmax = -3.0e38f;
#pragma unroll
  for (int i = 0; i < 4; ++i) {
    int m = i * 256 + t;
    int pos = (n << 9) + m - 256;
    float f = (((unsigned)pos < 16384u) && (m != 1023)) ? mask[pos] : 0.f;
    float lg = s[m] + logf(f + 1e-9f);
    fm[i] = f; logit[i] = lg;
    lmax = fmaxf(lmax, lg);
  }
#pragma unroll
  for (int o = 32; o; o >>= 1) lmax = fmaxf(lmax, __shfl_xor(lmax, o, 64));
  __shared__ float red[8];
  const int wv_ = t >> 6, ln = t & 63;
  if (ln == 0) red[wv_] = lmax;
  __syncthreads();
  const float gmax = fmaxf(fmaxf(red[0], red[1]), fmaxf(red[2], red[3]));

  float e[4], lsum = 0.f;
#pragma unroll
  for (int i = 0; i < 4; ++i) { e[i] = expf(logit[i] - gmax); lsum += e[i]; }
#pragma unroll
  for (int o = 32; o; o >>= 1) lsum += __shfl_xor(lsum, o, 64);
  __syncthreads();
  if (ln == 0) red[4 + wv_] = lsum;
  __syncthreads();
  const float inv = 1.f / ((red[4] + red[5]) + (red[6] + red[7]));
#pragma unroll
  for (int i = 0; i < 4; ++i) {
    int m = i * 256 + t;
    p[m] = f2bf(e[i] * inv * fm[i]);
  }
}

// -------------------------------------------------------------------- launch
extern "C" void kernel_launch(void* const* d_in, const int* in_sizes, int n_in,
                              void* d_out, int out_size, void* d_ws, size_t ws_size,
                              hipStream_t stream) {
  const float* x1 = (const float*)d_in[0];
  const float* mask = (const float*)d_in[2];
  const float* wq = (const float*)d_in[3];
  const float* bq = (const float*)d_in[4];
  const float* wk = (const float*)d_in[5];
  const float* bk = (const float*)d_in[6];
  const float* wv = (const float*)d_in[7];
  const float* bv = (const float*)d_in[8];
  const float* wo = (const float*)d_in[9];
  const float* bo = (const float*)d_in[10];

  char* ws = (char*)d_ws;
  unsigned short* xT   = (unsigned short*)(ws);
  unsigned short* attT = xT;                                     // alias
  unsigned short* Wqk  = (unsigned short*)(ws + 67108864);
  unsigned short* Wv   = (unsigned short*)(ws + 75497472);
  unsigned short* Wo   = (unsigned short*)(ws + 79691776);
  unsigned short* qkT  = (unsigned short*)(ws + 83886080);
  unsigned short* vbuf = (unsigned short*)(ws + 150994944);
  float*          Sbuf = (float*)(ws + 184549376);
  unsigned short* P    = (unsigned short*)(ws + 251658240);
  unsigned short* guard= (unsigned short*)(ws + 285212672);

  hipMemsetAsync(guard, 0, 4096, stream);

  transpose_x_k<<<dim3(512, 64), dim3(32, 8), 0, stream>>>(x1, xT);
  conv_w_k<<<dim3(32768), dim3(256), 0, stream>>>(wq, wk, wv, wo, Wqk, Wv, Wo);

  const int BIG = 0x40000000;
  // 1) qkT[16384][2048] = xT @ Wqk^T (+bias, q-part scaled 1/32)
  {
    GArgs a{};
    a.A = xT; a.Bt = Wqk; a.C = qkT;
    a.bias = bq; a.bias2 = bk; a.guard = guard;
    a.aBatch = 0; a.cBatch = 0;
    a.btRow0 = 0; a.btRow0Step = 0; a.btRowLim = BIG;
    a.btK0 = 0; a.btK0Step = 0; a.btKLim = BIG;
    gemm8_k<EPI_QK, 2048, 2048, 2048, 2048><<<dim3(8, 64, 1), 512, 0, stream>>>(a);
  }
  // 2) v[1024][16384] = Wv @ x (+bv)
  {
    GArgs a{};
    a.A = Wv; a.Bt = xT; a.C = vbuf;
    a.bias = bv; a.guard = guard;
    a.aBatch = 0; a.cBatch = 0;
    a.btRow0 = 0; a.btRow0Step = 0; a.btRowLim = BIG;
    a.btK0 = 0; a.btK0Step = 0; a.btKLim = BIG;
    gemm8_k<EPI_V, 2048, 2048, 16384, 2048><<<dim3(64, 4, 1), 512, 0, stream>>>(a);
  }
  // 3) S[n][512][1024] = Qb @ Kb^T (halo rows via guard)
  {
    GArgs a{};
    a.A = qkT; a.Bt = qkT; a.C = Sbuf;
    a.guard = guard;
    a.aBatch = 512 * 2048; a.cBatch = 512 * 1024;
    a.btRow0 = -256; a.btRow0Step = 512; a.btRowLim = 16384;
    a.btK0 = 1024; a.btK0Step = 0; a.btKLim = BIG;
    gemm8_k<EPI_S, 2048, 2048, 1024, 1024><<<dim3(4, 2, 32), 512, 0, stream>>>(a);
  }
  // 4) softmax rows -> P bf16
  softmax_k<<<dim3(16384), dim3(256), 0, stream>>>(Sbuf, mask, P);
  // 5) attT[n][512][1024] = relu(P @ Vb^T) (halo cols via guard)
  {
    GArgs a{};
    a.A = P; a.Bt = vbuf; a.C = attT;
    a.guard = guard;
    a.aBatch = 512 * 1024; a.cBatch = 512 * 1024;
    a.btRow0 = 0; a.btRow0Step = 0; a.btRowLim = BIG;
    a.btK0 = -256; a.btK0Step = 512; a.btKLim = 16384;
    gemm8_k<EPI_PV, 1024, 16384, 1024, 1024><<<dim3(4, 2, 32), 512, 0, stream>>>(a);
  }
  // 6) out[2048][16384] = (Wo @ attT^T + bo) * mask (fp32)
  {
    GArgs a{};
    a.A = Wo; a.Bt = attT; a.C = d_out;
    a.bias = bo; a.mask = mask; a.guard = guard;
    a.aBatch = 0; a.cBatch = 0;
    a.btRow0 = 0; a.btRow0Step = 0; a.btRowLim = BIG;
    a.btK0 = 0; a.btK0Step = 0; a.btKLim = BIG;
    gemm8_k<EPI_OUT, 1024, 1024, 16384, 1024><<<dim3(64, 8, 1), 512, 0, stream>>>(a);
  }
  (void)in_sizes; (void)n_in; (void)out_size; (void)ws_size;
}

// Round 5
// 469.307 us; speedup vs baseline: 1.6173x; 1.6173x over previous
//
// AttLayer block-local attention, MI355X gfx950.
// R5: revert K-loop to R2's proven schedule (reads in-phase, VM(6) at P3/P7,
//     SBAR->LGKM0->MFMA->SBAR, fa[4][2]: no spills). R4's fragment-prefetch
//     spilled (WRITE_SIZE 3x = scratch traffic, MfmaUtil 37->21). Keep only:
//     (a) XCD chunk swizzle (R4 counter-verified: FETCH 283->126 MB on QK),
//     (b) template<GUARDED>: guard-free stage path for QK/V/OUT.
// Workspace: xT | Wqk | Wv | Wo | qkT | v | S | P | guard (attT aliases xT).

#include <hip/hip_runtime.h>
#include <hip/hip_bf16.h>

typedef __attribute__((ext_vector_type(4))) float f32x4;
typedef __attribute__((ext_vector_type(8))) __bf16 bf16x8;

#define DEVINL static __device__ __forceinline__

DEVINL unsigned short f2bf(float f) {  // RTNE float->bf16
  union { float f; unsigned u; } x; x.f = f;
  return (unsigned short)((x.u + 0x7FFFu + ((x.u >> 16) & 1u)) >> 16);
}

DEVINL void gload16(const void* g, void* l) {
  __builtin_amdgcn_global_load_lds((const __attribute__((address_space(1))) void*)g,
                                   (__attribute__((address_space(3))) void*)l,
                                   16, 0, 0);
}

#define SBAR()   asm volatile("s_barrier" ::: "memory")
#define LGKM0()  asm volatile("s_waitcnt lgkmcnt(0)" ::: "memory")
#define VM(n)    asm volatile("s_waitcnt vmcnt(" #n ")" ::: "memory")

// ---------------------------------------------------------------- transpose x
__global__ __launch_bounds__(256) void transpose_x_k(const float* __restrict__ x,
                                                     unsigned short* __restrict__ xT) {
  __shared__ float tile[32][33];
  const int bx = blockIdx.x;  // 512
  const int by = blockIdx.y;  // 64
  const int tx = threadIdx.x; // 32
  const int ty = threadIdx.y; // 8
#pragma unroll
  for (int i = 0; i < 4; ++i) {
    int c = by * 32 + ty + i * 8;
    tile[ty + i * 8][tx] = x[(long)c * 16384 + bx * 32 + tx];
  }
  __syncthreads();
#pragma unroll
  for (int i = 0; i < 4; ++i) {
    int l = bx * 32 + ty + i * 8;
    xT[(long)l * 2048 + by * 32 + tx] = f2bf(tile[tx][ty + i * 8]);
  }
}

// ------------------------------------------------------------ weight convert
__global__ __launch_bounds__(256) void conv_w_k(const float* __restrict__ wq,
                                                const float* __restrict__ wk,
                                                const float* __restrict__ wv,
                                                const float* __restrict__ wo,
                                                unsigned short* __restrict__ Wqk,
                                                unsigned short* __restrict__ Wv,
                                                unsigned short* __restrict__ Wo) {
  long i = (long)blockIdx.x * 256 + threadIdx.x;
  if (i < 4194304) {
    float s = (i < 2097152) ? wq[i] : wk[i - 2097152];
    Wqk[i] = f2bf(s);
  } else if (i < 6291456) {
    Wv[i - 4194304] = f2bf(wv[i - 4194304]);
  } else {
    Wo[i - 6291456] = f2bf(wo[i - 6291456]);
  }
}

// ------------------------------------------------------------------ GEMM core
enum { EPI_QK = 0, EPI_V = 1, EPI_S = 2, EPI_PV = 3, EPI_OUT = 4 };

struct GArgs {
  const unsigned short* A;
  const unsigned short* Bt;
  void* C;
  const float* bias;
  const float* bias2;
  const float* mask;
  const unsigned short* guard;
  int aBatch, cBatch;
  int btRow0, btRow0Step, btRowLim;
  int btK0, btK0Step, btKLim;
};

// 256x256 tile, BK=64, 8 waves (2M x 4N), per-wave 128x64, 8-phase pipeline.
template <int EPI, int GUARDED, int LDA, int LDB, int LDC, int KK>
__global__ __launch_bounds__(512, 2) void gemm8_k(GArgs g) {
  constexpr int NK = KK >> 6;
  constexpr int NT = NK >> 1;
  __shared__ char lds[131072];

  const int t = threadIdx.x;
  const int l = t & 63;
  const int w = t >> 6;

  // XCD chunk swizzle (all grids % 8 == 0): each XCD gets a contiguous chunk.
  const int gx = gridDim.x, gxy = gx * gridDim.y;
  const int nwg = gxy * gridDim.z;
  int lin = blockIdx.z * gxy + blockIdx.y * gx + blockIdx.x;
  lin = (lin & 7) * (nwg >> 3) + (lin >> 3);
  const int z = lin / gxy;
  const int rres = lin - z * gxy;
  const int Mbase = (rres / gx) << 8;
  const int Nbase = (rres - (rres / gx) * gx) << 8;

  const int wr = w >> 2;
  const int wc = w & 3;
  const int fr = l & 15;
  const int fg = l >> 4;

  const unsigned short* Ab = g.A + (long)z * g.aBatch + (long)Mbase * LDA;
  const int bRowBase = g.btRow0 + z * g.btRow0Step + Nbase;
  const int bK0 = g.btK0 + z * g.btK0Step;

  const int rr = t >> 3;
  const int cb8s = t & 7;

  // stage one 16 KiB unit (2 gloads/thread) of K-tile kt into buf.
  // unit 0: A rows 0-63,128-191   unit 3: A rows 64-127,192-255
  // unit 1: B rows {0-31,64-95},{128-159,192-223}
  // unit 2: B rows {32-63,96-127},{160-191,224-255}
  auto stage = [&](int bufSel, int unit, int kt) {
    const int k0 = (kt & (NK - 1)) << 6;
    const bool isA = (unit == 0) || (unit == 3);
#pragma unroll
    for (int gph = 0; gph < 2; ++gph) {
      int row;
      if (isA) row = (unit == 0 ? 0 : 64) + (gph << 7) + rr;
      else     row = (unit == 1 ? 0 : 32) + (gph << 7) + (rr & 31) + ((rr >> 5) << 6);
      const int cbL = cb8s ^ (row & 7);
      const int gk = k0 + (cbL << 3);
      char* lp = lds + (bufSel << 16) + (isA ? 0 : 32768) + row * 128 + (cb8s << 4);
      const char* gp;
      if (isA) {
        gp = (const char*)(Ab + (long)row * LDA + gk);
      } else if (!GUARDED) {
        gp = (const char*)(g.Bt + (long)(bRowBase + row) * LDB + (bK0 + gk));
      } else {
        const int grow = bRowBase + row;
        const int gkk = bK0 + gk;
        if ((unsigned)grow < (unsigned)g.btRowLim && (unsigned)gkk < (unsigned)g.btKLim)
          gp = (const char*)(g.Bt + (long)grow * LDB + gkk);
        else
          gp = (const char*)g.guard + (l << 4);
      }
      gload16(gp, lp);
    }
  };

  const int arow = (wr << 7) + fr;
  const int brow = (wc << 6) + fr;

  auto ldA = [&](int i8, int kk, int bufSel) -> bf16x8 {
    const int row = arow + (i8 << 4);
    const int cb = ((kk << 2) | fg) ^ (row & 7);
    return *(const bf16x8*)(lds + (bufSel << 16) + row * 128 + (cb << 4));
  };
  auto ldB = [&](int j, int kk, int bufSel) -> bf16x8 {
    const int row = brow + (j << 4);
    const int cb = ((kk << 2) | fg) ^ (row & 7);
    return *(const bf16x8*)(lds + (bufSel << 16) + 32768 + row * 128 + (cb << 4));
  };

  f32x4 acc[8][4];
#pragma unroll
  for (int i = 0; i < 8; ++i)
#pragma unroll
    for (int j = 0; j < 4; ++j) acc[i][j] = f32x4{0.f, 0.f, 0.f, 0.f};

  // prologue: buf0 fully (kt0), buf1 units 0-2 (kt1). 14 gloads in flight.
  stage(0, 0, 0); stage(0, 1, 0); stage(0, 2, 0); stage(0, 3, 0);
  stage(1, 0, 1); stage(1, 1, 1); stage(1, 2, 1);
  VM(6);        // oldest 8 (all of buf0) landed; buf1's 6 stay in flight
  SBAR();

  bf16x8 fa[4][2], fb[4][2];

#define MFMA_Q(QI, QJ)                                                        \
  __builtin_amdgcn_s_setprio(1);                                              \
  _Pragma("unroll") for (int i = 0; i < 4; ++i)                               \
  _Pragma("unroll") for (int j = 0; j < 2; ++j)                               \
  _Pragma("unroll") for (int kk = 0; kk < 2; ++kk)                            \
    acc[(QI)*4 + i][(QJ)*2 + j] = __builtin_amdgcn_mfma_f32_16x16x32_bf16(    \
        fa[i][kk], fb[(QJ)*2 + j][kk], acc[(QI)*4 + i][(QJ)*2 + j], 0, 0, 0); \
  __builtin_amdgcn_s_setprio(0);

#pragma unroll 1
  for (int it = 0; it < NT; ++it) {
    const int kt1 = 2 * it + 1;
    const int ktn0 = 2 * it + 2;
    const int ktn1 = 2 * it + 3;
    // ---- phase 0 (buf0, quadrant 0,0)
#pragma unroll
    for (int i = 0; i < 4; ++i) { fa[i][0] = ldA(i, 0, 0); fa[i][1] = ldA(i, 1, 0); }
#pragma unroll
    for (int j = 0; j < 2; ++j) { fb[j][0] = ldB(j, 0, 0); fb[j][1] = ldB(j, 1, 0); }
    stage(1, 3, kt1);
    SBAR(); LGKM0();
    MFMA_Q(0, 0);
    SBAR();
    // ---- phase 1 (buf0, quadrant 0,1)
#pragma unroll
    for (int j = 2; j < 4; ++j) { fb[j][0] = ldB(j, 0, 0); fb[j][1] = ldB(j, 1, 0); }
    stage(0, 0, ktn0);
    SBAR(); LGKM0();
    MFMA_Q(0, 1);
    SBAR();
    // ---- phase 2 (buf0, quadrant 1,0)
#pragma unroll
    for (int i = 0; i < 4; ++i) { fa[i][0] = ldA(4 + i, 0, 0); fa[i][1] = ldA(4 + i, 1, 0); }
    stage(0, 1, ktn0);
    SBAR(); LGKM0();
    MFMA_Q(1, 0);
    SBAR();
    // ---- phase 3 (buf0, quadrant 1,1)
    stage(0, 2, ktn0);
    SBAR(); LGKM0();
    MFMA_Q(1, 1);
    VM(6);       // buf1 (kt1) fully landed before phase 4
    SBAR();
    // ---- phase 4 (buf1, quadrant 0,0)
#pragma unroll
    for (int i = 0; i < 4; ++i) { fa[i][0] = ldA(i, 0, 1); fa[i][1] = ldA(i, 1, 1); }
#pragma unroll
    for (int j = 0; j < 2; ++j) { fb[j][0] = ldB(j, 0, 1); fb[j][1] = ldB(j, 1, 1); }
    stage(0, 3, ktn0);
    SBAR(); LGKM0();
    MFMA_Q(0, 0);
    SBAR();
    // ---- phase 5 (buf1, quadrant 0,1)
#pragma unroll
    for (int j = 2; j < 4; ++j) { fb[j][0] = ldB(j, 0, 1); fb[j][1] = ldB(j, 1, 1); }
    stage(1, 0, ktn1);
    SBAR(); LGKM0();
    MFMA_Q(0, 1);
    SBAR();
    // ---- phase 6 (buf1, quadrant 1,0)
#pragma unroll
    for (int i = 0; i < 4; ++i) { fa[i][0] = ldA(4 + i, 0, 1); fa[i][1] = ldA(4 + i, 1, 1); }
    stage(1, 1, ktn1);
    SBAR(); LGKM0();
    MFMA_Q(1, 0);
    SBAR();
    // ---- phase 7 (buf1, quadrant 1,1)
    stage(1, 2, ktn1);
    SBAR(); LGKM0();
    MFMA_Q(1, 1);
    VM(6);       // buf0 (ktn0) fully landed before next phase 0
    SBAR();
  }
  VM(0); LGKM0(); SBAR();  // drain wrapped prefetches before epilogue

  // epilogue: D row=(lane>>4)*4+r, col=lane&15 within each 16x16 fragment
#pragma unroll
  for (int ii = 0; ii < 8; ++ii)
#pragma unroll
    for (int j = 0; j < 4; ++j)
#pragma unroll
      for (int r = 0; r < 4; ++r) {
        const int row = Mbase + (wr << 7) + ii * 16 + fg * 4 + r;
        const int col = Nbase + (wc << 6) + j * 16 + fr;
        float val = acc[ii][j][r];
        const long off = (long)z * g.cBatch + (long)row * LDC + col;
        if (EPI == EPI_QK) {
          val = (col < 1024) ? (val + g.bias[col]) * 0.03125f
                             : (val + g.bias2[col - 1024]);
          ((unsigned short*)g.C)[off] = f2bf(val);
        } else if (EPI == EPI_V) {
          val += g.bias[row];
          ((unsigned short*)g.C)[off] = f2bf(val);
        } else if (EPI == EPI_S) {
          ((float*)g.C)[off] = val;
        } else if (EPI == EPI_PV) {
          val = fmaxf(val, 0.f);
          ((unsigned short*)g.C)[off] = f2bf(val);
        } else {
          val = (val + g.bias[row]) * g.mask[col];
          ((float*)g.C)[off] = val;
        }
      }
#undef MFMA_Q
}

// ------------------------------------------------------------------- softmax
__global__ __launch_bounds__(256) void softmax_k(const float* __restrict__ S,
                                                 const float* __restrict__ mask,
                                                 unsigned short* __restrict__ P) {
  const int row = blockIdx.x;
  const int n = row >> 9;
  const float* s = S + (long)row * 1024;
  unsigned short* p = P + (long)row * 1024;
  const int t = threadIdx.x;

  float logit[4], fm[4];
  float lmax = -3.0e38f;
#pragma unroll
  for (int i = 0; i < 4; ++i) {
    int m = i * 256 + t;
    int pos = (n << 9) + m - 256;
    float f = (((unsigned)pos < 16384u) && (m != 1023)) ? mask[pos] : 0.f;
    float lg = s[m] + logf(f + 1e-9f);
    fm[i] = f; logit[i] = lg;
    lmax = fmaxf(lmax, lg);
  }
#pragma unroll
  for (int o = 32; o; o >>= 1) lmax = fmaxf(lmax, __shfl_xor(lmax, o, 64));
  __shared__ float red[8];
  const int wv_ = t >> 6, ln = t & 63;
  if (ln == 0) red[wv_] = lmax;
  __syncthreads();
  const float gmax = fmaxf(fmaxf(red[0], red[1]), fmaxf(red[2], red[3]));

  float e[4], lsum = 0.f;
#pragma unroll
  for (int i = 0; i < 4; ++i) { e[i] = expf(logit[i] - gmax); lsum += e[i]; }
#pragma unroll
  for (int o = 32; o; o >>= 1) lsum += __shfl_xor(lsum, o, 64);
  __syncthreads();
  if (ln == 0) red[4 + wv_] = lsum;
  __syncthreads();
  const float inv = 1.f / ((red[4] + red[5]) + (red[6] + red[7]));
#pragma unroll
  for (int i = 0; i < 4; ++i) {
    int m = i * 256 + t;
    p[m] = f2bf(e[i] * inv * fm[i]);
  }
}

// -------------------------------------------------------------------- launch
extern "C" void kernel_launch(void* const* d_in, const int* in_sizes, int n_in,
                              void* d_out, int out_size, void* d_ws, size_t ws_size,
                              hipStream_t stream) {
  const float* x1 = (const float*)d_in[0];
  const float* mask = (const float*)d_in[2];
  const float* wq = (const float*)d_in[3];
  const float* bq = (const float*)d_in[4];
  const float* wk = (const float*)d_in[5];
  const float* bk = (const float*)d_in[6];
  const float* wv = (const float*)d_in[7];
  const float* bv = (const float*)d_in[8];
  const float* wo = (const float*)d_in[9];
  const float* bo = (const float*)d_in[10];

  char* ws = (char*)d_ws;
  unsigned short* xT   = (unsigned short*)(ws);
  unsigned short* attT = xT;                                     // alias
  unsigned short* Wqk  = (unsigned short*)(ws + 67108864);
  unsigned short* Wv   = (unsigned short*)(ws + 75497472);
  unsigned short* Wo   = (unsigned short*)(ws + 79691776);
  unsigned short* qkT  = (unsigned short*)(ws + 83886080);
  unsigned short* vbuf = (unsigned short*)(ws + 150994944);
  float*          Sbuf = (float*)(ws + 184549376);
  unsigned short* P    = (unsigned short*)(ws + 251658240);
  unsigned short* guard= (unsigned short*)(ws + 285212672);

  hipMemsetAsync(guard, 0, 4096, stream);

  transpose_x_k<<<dim3(512, 64), dim3(32, 8), 0, stream>>>(x1, xT);
  conv_w_k<<<dim3(32768), dim3(256), 0, stream>>>(wq, wk, wv, wo, Wqk, Wv, Wo);

  const int BIG = 0x40000000;
  // 1) qkT[16384][2048] = xT @ Wqk^T (+bias, q-part scaled 1/32)
  {
    GArgs a{};
    a.A = xT; a.Bt = Wqk; a.C = qkT;
    a.bias = bq; a.bias2 = bk; a.guard = guard;
    a.aBatch = 0; a.cBatch = 0;
    a.btRow0 = 0; a.btRow0Step = 0; a.btRowLim = BIG;
    a.btK0 = 0; a.btK0Step = 0; a.btKLim = BIG;
    gemm8_k<EPI_QK, 0, 2048, 2048, 2048, 2048><<<dim3(8, 64, 1), 512, 0, stream>>>(a);
  }
  // 2) v[1024][16384] = Wv @ x (+bv)
  {
    GArgs a{};
    a.A = Wv; a.Bt = xT; a.C = vbuf;
    a.bias = bv; a.guard = guard;
    a.aBatch = 0; a.cBatch = 0;
    a.btRow0 = 0; a.btRow0Step = 0; a.btRowLim = BIG;
    a.btK0 = 0; a.btK0Step = 0; a.btKLim = BIG;
    gemm8_k<EPI_V, 0, 2048, 2048, 16384, 2048><<<dim3(64, 4, 1), 512, 0, stream>>>(a);
  }
  // 3) S[n][512][1024] = Qb @ Kb^T (halo rows via guard)
  {
    GArgs a{};
    a.A = qkT; a.Bt = qkT; a.C = Sbuf;
    a.guard = guard;
    a.aBatch = 512 * 2048; a.cBatch = 512 * 1024;
    a.btRow0 = -256; a.btRow0Step = 512; a.btRowLim = 16384;
    a.btK0 = 1024; a.btK0Step = 0; a.btKLim = BIG;
    gemm8_k<EPI_S, 1, 2048, 2048, 1024, 1024><<<dim3(4, 2, 32), 512, 0, stream>>>(a);
  }
  // 4) softmax rows -> P bf16
  softmax_k<<<dim3(16384), dim3(256), 0, stream>>>(Sbuf, mask, P);
  // 5) attT[n][512][1024] = relu(P @ Vb^T) (halo cols via guard)
  {
    GArgs a{};
    a.A = P; a.Bt = vbuf; a.C = attT;
    a.guard = guard;
    a.aBatch = 512 * 1024; a.cBatch = 512 * 1024;
    a.btRow0 = 0; a.btRow0Step = 0; a.btRowLim = BIG;
    a.btK0 = -256; a.btK0Step = 512; a.btKLim = 16384;
    gemm8_k<EPI_PV, 1, 1024, 16384, 1024, 1024><<<dim3(4, 2, 32), 512, 0, stream>>>(a);
  }
  // 6) out[2048][16384] = (Wo @ attT^T + bo) * mask (fp32)
  {
    GArgs a{};
    a.A = Wo; a.Bt = attT; a.C = d_out;
    a.bias = bo; a.mask = mask; a.guard = guard;
    a.aBatch = 0; a.cBatch = 0;
    a.btRow0 = 0; a.btRow0Step = 0; a.btRowLim = BIG;
    a.btK0 = 0; a.btK0Step = 0; a.btKLim = BIG;
    gemm8_k<EPI_OUT, 0, 1024, 1024, 16384, 1024><<<dim3(64, 8, 1), 512, 0, stream>>>(a);
  }
  (void)in_sizes; (void)n_in; (void)out_size; (void)ws_size;
}

// Round 6
// 463.971 us; speedup vs baseline: 1.6359x; 1.0115x over previous
//
// AttLayer block-local attention, MI355X gfx950.
// R6: R5 schedule (verified) + issue-efficiency micro-opts:
//   - MQ: kk-outer MFMA order (dependent-MFMA spacing 1 -> 8; same numerics)
//   - LGKM(8) pre-barrier pacing hint on 12-read phases (m201 template)
//   - vectorized transpose (ushort4 stores), softmax (float4/ushort4),
//     conv_w (float4/ushort4)  [Guideline 13]
// Schedule/sync structure byte-identical to R5 (no new hazards).
// Workspace: xT | Wqk | Wv | Wo | qkT | v | S | P | guard (attT aliases xT).

#include <hip/hip_runtime.h>
#include <hip/hip_bf16.h>

typedef __attribute__((ext_vector_type(4))) float f32x4;
typedef __attribute__((ext_vector_type(8))) __bf16 bf16x8;

struct ushort4_t { unsigned short x, y, z, w; };

#define DEVINL static __device__ __forceinline__

DEVINL unsigned short f2bf(float f) {  // RTNE float->bf16
  union { float f; unsigned u; } x; x.f = f;
  return (unsigned short)((x.u + 0x7FFFu + ((x.u >> 16) & 1u)) >> 16);
}

DEVINL void gload16(const void* g, void* l) {
  __builtin_amdgcn_global_load_lds((const __attribute__((address_space(1))) void*)g,
                                   (__attribute__((address_space(3))) void*)l,
                                   16, 0, 0);
}

#define SBAR()   asm volatile("s_barrier" ::: "memory")
#define LGKM0()  asm volatile("s_waitcnt lgkmcnt(0)" ::: "memory")
#define LGKM8()  asm volatile("s_waitcnt lgkmcnt(8)" ::: "memory")
#define VM(n)    asm volatile("s_waitcnt vmcnt(" #n ")" ::: "memory")

// ---------------------------------------------------------------- transpose x
// x1 [2048][16384] f32 -> xT [16384][2048] bf16 (RTNE), ushort4 stores
__global__ __launch_bounds__(256) void transpose_x_k(const float* __restrict__ x,
                                                     unsigned short* __restrict__ xT) {
  __shared__ float tile[32][33];
  const int bx = blockIdx.x;  // 512
  const int by = blockIdx.y;  // 64
  const int tx = threadIdx.x; // 32
  const int ty = threadIdx.y; // 8
#pragma unroll
  for (int i = 0; i < 4; ++i) {
    int c = by * 32 + ty + i * 8;
    tile[ty + i * 8][tx] = x[(long)c * 16384 + bx * 32 + tx];
  }
  __syncthreads();
  const int t = ty * 32 + tx;
  const int lrow = t >> 3;          // 0..31 (l within tile)
  const int cq = (t & 7) << 2;      // 0..28 (channel quad)
  ushort4_t o;
  o.x = f2bf(tile[cq + 0][lrow]);
  o.y = f2bf(tile[cq + 1][lrow]);
  o.z = f2bf(tile[cq + 2][lrow]);
  o.w = f2bf(tile[cq + 3][lrow]);
  *reinterpret_cast<ushort4_t*>(xT + (long)(bx * 32 + lrow) * 2048 + by * 32 + cq) = o;
}

// ------------------------------------------------------------ weight convert
// 2097152 elements per 8.4M/4 thread-grid chunk; all boundaries %4 == 0.
__global__ __launch_bounds__(256) void conv_w_k(const float* __restrict__ wq,
                                                const float* __restrict__ wk,
                                                const float* __restrict__ wv,
                                                const float* __restrict__ wo,
                                                unsigned short* __restrict__ Wqk,
                                                unsigned short* __restrict__ Wv,
                                                unsigned short* __restrict__ Wo) {
  long i = ((long)blockIdx.x * 256 + threadIdx.x) * 4;   // 0..8388604
  const float* src;
  unsigned short* dst;
  if (i < 4194304) {
    src = (i < 2097152) ? (wq + i) : (wk + i - 2097152);
    dst = Wqk + i;
  } else if (i < 6291456) {
    src = wv + (i - 4194304);
    dst = Wv + (i - 4194304);
  } else {
    src = wo + (i - 6291456);
    dst = Wo + (i - 6291456);
  }
  float4 v = *reinterpret_cast<const float4*>(src);
  ushort4_t o{f2bf(v.x), f2bf(v.y), f2bf(v.z), f2bf(v.w)};
  *reinterpret_cast<ushort4_t*>(dst) = o;
}

// ------------------------------------------------------------------ GEMM core
enum { EPI_QK = 0, EPI_V = 1, EPI_S = 2, EPI_PV = 3, EPI_OUT = 4 };

struct GArgs {
  const unsigned short* A;
  const unsigned short* Bt;
  void* C;
  const float* bias;
  const float* bias2;
  const float* mask;
  const unsigned short* guard;
  int aBatch, cBatch;
  int btRow0, btRow0Step, btRowLim;
  int btK0, btK0Step, btKLim;
};

// 256x256 tile, BK=64, 8 waves (2M x 4N), per-wave 128x64, 8-phase pipeline.
template <int EPI, int GUARDED, int LDA, int LDB, int LDC, int KK>
__global__ __launch_bounds__(512, 2) void gemm8_k(GArgs g) {
  constexpr int NK = KK >> 6;
  constexpr int NT = NK >> 1;
  __shared__ char lds[131072];

  const int t = threadIdx.x;
  const int l = t & 63;
  const int w = t >> 6;

  // XCD chunk swizzle (all grids % 8 == 0): each XCD gets a contiguous chunk.
  const int gx = gridDim.x, gxy = gx * gridDim.y;
  const int nwg = gxy * gridDim.z;
  int lin = blockIdx.z * gxy + blockIdx.y * gx + blockIdx.x;
  lin = (lin & 7) * (nwg >> 3) + (lin >> 3);
  const int z = lin / gxy;
  const int rres = lin - z * gxy;
  const int Mbase = (rres / gx) << 8;
  const int Nbase = (rres - (rres / gx) * gx) << 8;

  const int wr = w >> 2;
  const int wc = w & 3;
  const int fr = l & 15;
  const int fg = l >> 4;

  const unsigned short* Ab = g.A + (long)z * g.aBatch + (long)Mbase * LDA;
  const int bRowBase = g.btRow0 + z * g.btRow0Step + Nbase;
  const int bK0 = g.btK0 + z * g.btK0Step;

  const int rr = t >> 3;
  const int cb8s = t & 7;

  // stage one 16 KiB unit (2 gloads/thread) of K-tile kt into buf.
  // unit 0: A rows 0-63,128-191   unit 3: A rows 64-127,192-255
  // unit 1: B rows {0-31,64-95},{128-159,192-223}
  // unit 2: B rows {32-63,96-127},{160-191,224-255}
  auto stage = [&](int bufSel, int unit, int kt) {
    const int k0 = (kt & (NK - 1)) << 6;
    const bool isA = (unit == 0) || (unit == 3);
#pragma unroll
    for (int gph = 0; gph < 2; ++gph) {
      int row;
      if (isA) row = (unit == 0 ? 0 : 64) + (gph << 7) + rr;
      else     row = (unit == 1 ? 0 : 32) + (gph << 7) + (rr & 31) + ((rr >> 5) << 6);
      const int cbL = cb8s ^ (row & 7);
      const int gk = k0 + (cbL << 3);
      char* lp = lds + (bufSel << 16) + (isA ? 0 : 32768) + row * 128 + (cb8s << 4);
      const char* gp;
      if (isA) {
        gp = (const char*)(Ab + (long)row * LDA + gk);
      } else if (!GUARDED) {
        gp = (const char*)(g.Bt + (long)(bRowBase + row) * LDB + (bK0 + gk));
      } else {
        const int grow = bRowBase + row;
        const int gkk = bK0 + gk;
        if ((unsigned)grow < (unsigned)g.btRowLim && (unsigned)gkk < (unsigned)g.btKLim)
          gp = (const char*)(g.Bt + (long)grow * LDB + gkk);
        else
          gp = (const char*)g.guard + (l << 4);
      }
      gload16(gp, lp);
    }
  };

  const int arow = (wr << 7) + fr;
  const int brow = (wc << 6) + fr;

  auto ldA = [&](int i8, int kk, int bufSel) -> bf16x8 {
    const int row = arow + (i8 << 4);
    const int cb = ((kk << 2) | fg) ^ (row & 7);
    return *(const bf16x8*)(lds + (bufSel << 16) + row * 128 + (cb << 4));
  };
  auto ldB = [&](int j, int kk, int bufSel) -> bf16x8 {
    const int row = brow + (j << 4);
    const int cb = ((kk << 2) | fg) ^ (row & 7);
    return *(const bf16x8*)(lds + (bufSel << 16) + 32768 + row * 128 + (cb << 4));
  };

  f32x4 acc[8][4];
#pragma unroll
  for (int i = 0; i < 8; ++i)
#pragma unroll
    for (int j = 0; j < 4; ++j) acc[i][j] = f32x4{0.f, 0.f, 0.f, 0.f};

  // prologue: buf0 fully (kt0), buf1 units 0-2 (kt1). 14 gloads in flight.
  stage(0, 0, 0); stage(0, 1, 0); stage(0, 2, 0); stage(0, 3, 0);
  stage(1, 0, 1); stage(1, 1, 1); stage(1, 2, 1);
  VM(6);        // oldest 8 (all of buf0) landed; buf1's 6 stay in flight
  SBAR();

  bf16x8 fa[4][2], fb[4][2];

// kk-outer: dependent MFMAs on the same acc are spaced 8 apart.
#define MFMA_Q(QI, QJ)                                                        \
  __builtin_amdgcn_s_setprio(1);                                              \
  _Pragma("unroll") for (int kk = 0; kk < 2; ++kk)                            \
  _Pragma("unroll") for (int i = 0; i < 4; ++i)                               \
  _Pragma("unroll") for (int j = 0; j < 2; ++j)                               \
    acc[(QI)*4 + i][(QJ)*2 + j] = __builtin_amdgcn_mfma_f32_16x16x32_bf16(    \
        fa[i][kk], fb[(QJ)*2 + j][kk], acc[(QI)*4 + i][(QJ)*2 + j], 0, 0, 0); \
  __builtin_amdgcn_s_setprio(0);

#pragma unroll 1
  for (int it = 0; it < NT; ++it) {
    const int kt1 = 2 * it + 1;
    const int ktn0 = 2 * it + 2;
    const int ktn1 = 2 * it + 3;
    // ---- phase 0 (buf0, quadrant 0,0) — 12 reads: lgkm(8) pacing hint
#pragma unroll
    for (int i = 0; i < 4; ++i) { fa[i][0] = ldA(i, 0, 0); fa[i][1] = ldA(i, 1, 0); }
#pragma unroll
    for (int j = 0; j < 2; ++j) { fb[j][0] = ldB(j, 0, 0); fb[j][1] = ldB(j, 1, 0); }
    stage(1, 3, kt1);
    LGKM8();
    SBAR(); LGKM0();
    MFMA_Q(0, 0);
    SBAR();
    // ---- phase 1 (buf0, quadrant 0,1)
#pragma unroll
    for (int j = 2; j < 4; ++j) { fb[j][0] = ldB(j, 0, 0); fb[j][1] = ldB(j, 1, 0); }
    stage(0, 0, ktn0);
    SBAR(); LGKM0();
    MFMA_Q(0, 1);
    SBAR();
    // ---- phase 2 (buf0, quadrant 1,0)
#pragma unroll
    for (int i = 0; i < 4; ++i) { fa[i][0] = ldA(4 + i, 0, 0); fa[i][1] = ldA(4 + i, 1, 0); }
    stage(0, 1, ktn0);
    SBAR(); LGKM0();
    MFMA_Q(1, 0);
    SBAR();
    // ---- phase 3 (buf0, quadrant 1,1)
    stage(0, 2, ktn0);
    SBAR(); LGKM0();
    MFMA_Q(1, 1);
    VM(6);       // buf1 (kt1) fully landed before phase 4
    SBAR();
    // ---- phase 4 (buf1, quadrant 0,0) — 12 reads: lgkm(8) pacing hint
#pragma unroll
    for (int i = 0; i < 4; ++i) { fa[i][0] = ldA(i, 0, 1); fa[i][1] = ldA(i, 1, 1); }
#pragma unroll
    for (int j = 0; j < 2; ++j) { fb[j][0] = ldB(j, 0, 1); fb[j][1] = ldB(j, 1, 1); }
    stage(0, 3, ktn0);
    LGKM8();
    SBAR(); LGKM0();
    MFMA_Q(0, 0);
    SBAR();
    // ---- phase 5 (buf1, quadrant 0,1)
#pragma unroll
    for (int j = 2; j < 4; ++j) { fb[j][0] = ldB(j, 0, 1); fb[j][1] = ldB(j, 1, 1); }
    stage(1, 0, ktn1);
    SBAR(); LGKM0();
    MFMA_Q(0, 1);
    SBAR();
    // ---- phase 6 (buf1, quadrant 1,0)
#pragma unroll
    for (int i = 0; i < 4; ++i) { fa[i][0] = ldA(4 + i, 0, 1); fa[i][1] = ldA(4 + i, 1, 1); }
    stage(1, 1, ktn1);
    SBAR(); LGKM0();
    MFMA_Q(1, 0);
    SBAR();
    // ---- phase 7 (buf1, quadrant 1,1)
    stage(1, 2, ktn1);
    SBAR(); LGKM0();
    MFMA_Q(1, 1);
    VM(6);       // buf0 (ktn0) fully landed before next phase 0
    SBAR();
  }
  VM(0); LGKM0(); SBAR();  // drain wrapped prefetches before epilogue

  // epilogue: D row=(lane>>4)*4+r, col=lane&15 within each 16x16 fragment
#pragma unroll
  for (int ii = 0; ii < 8; ++ii)
#pragma unroll
    for (int j = 0; j < 4; ++j)
#pragma unroll
      for (int r = 0; r < 4; ++r) {
        const int row = Mbase + (wr << 7) + ii * 16 + fg * 4 + r;
        const int col = Nbase + (wc << 6) + j * 16 + fr;
        float val = acc[ii][j][r];
        const long off = (long)z * g.cBatch + (long)row * LDC + col;
        if (EPI == EPI_QK) {
          val = (col < 1024) ? (val + g.bias[col]) * 0.03125f
                             : (val + g.bias2[col - 1024]);
          ((unsigned short*)g.C)[off] = f2bf(val);
        } else if (EPI == EPI_V) {
          val += g.bias[row];
          ((unsigned short*)g.C)[off] = f2bf(val);
        } else if (EPI == EPI_S) {
          ((float*)g.C)[off] = val;
        } else if (EPI == EPI_PV) {
          val = fmaxf(val, 0.f);
          ((unsigned short*)g.C)[off] = f2bf(val);
        } else {
          val = (val + g.bias[row]) * g.mask[col];
          ((float*)g.C)[off] = val;
        }
      }
#undef MFMA_Q
}

// ------------------------------------------------------------------- softmax
// S [16384][1024] f32 -> P bf16; thread t owns cols 4t..4t+3 (vectorized).
// mask float4 per thread is all-in-range or all-OOB (alignment: n*512-256+4t).
__global__ __launch_bounds__(256) void softmax_k(const float* __restrict__ S,
                                                 const float* __restrict__ mask,
                                                 unsigned short* __restrict__ P) {
  const int row = blockIdx.x;      // n*512 + l
  const int n = row >> 9;
  const float* s = S + (long)row * 1024;
  unsigned short* p = P + (long)row * 1024;
  const int t = threadIdx.x;

  const float4 sv = *reinterpret_cast<const float4*>(s + t * 4);
  const int pos0 = (n << 9) + t * 4 - 256;
  float4 mv = {0.f, 0.f, 0.f, 0.f};
  if ((unsigned)pos0 < 16384u) mv = *reinterpret_cast<const float4*>(mask + pos0);
  float fm[4] = {mv.x, mv.y, mv.z, mv.w};
  if (t == 255) fm[3] = 0.f;       // m == 1023 excluded by window mask
  const float sc[4] = {sv.x, sv.y, sv.z, sv.w};

  float logit[4];
  float lmax = -3.0e38f;
#pragma unroll
  for (int k = 0; k < 4; ++k) {
    logit[k] = sc[k] + logf(fm[k] + 1e-9f);
    lmax = fmaxf(lmax, logit[k]);
  }
#pragma unroll
  for (int o = 32; o; o >>= 1) lmax = fmaxf(lmax, __shfl_xor(lmax, o, 64));
  __shared__ float red[8];
  const int wv_ = t >> 6, ln = t & 63;
  if (ln == 0) red[wv_] = lmax;
  __syncthreads();
  const float gmax = fmaxf(fmaxf(red[0], red[1]), fmaxf(red[2], red[3]));

  float e[4], lsum = 0.f;
#pragma unroll
  for (int k = 0; k < 4; ++k) { e[k] = expf(logit[k] - gmax); lsum += e[k]; }
#pragma unroll
  for (int o = 32; o; o >>= 1) lsum += __shfl_xor(lsum, o, 64);
  if (ln == 0) red[4 + wv_] = lsum;
  __syncthreads();
  const float inv = 1.f / ((red[4] + red[5]) + (red[6] + red[7]));
  ushort4_t o4;
  o4.x = f2bf(e[0] * inv * fm[0]);
  o4.y = f2bf(e[1] * inv * fm[1]);
  o4.z = f2bf(e[2] * inv * fm[2]);
  o4.w = f2bf(e[3] * inv * fm[3]);
  *reinterpret_cast<ushort4_t*>(p + t * 4) = o4;
}

// -------------------------------------------------------------------- launch
extern "C" void kernel_launch(void* const* d_in, const int* in_sizes, int n_in,
                              void* d_out, int out_size, void* d_ws, size_t ws_size,
                              hipStream_t stream) {
  const float* x1 = (const float*)d_in[0];
  const float* mask = (const float*)d_in[2];
  const float* wq = (const float*)d_in[3];
  const float* bq = (const float*)d_in[4];
  const float* wk = (const float*)d_in[5];
  const float* bk = (const float*)d_in[6];
  const float* wv = (const float*)d_in[7];
  const float* bv = (const float*)d_in[8];
  const float* wo = (const float*)d_in[9];
  const float* bo = (const float*)d_in[10];

  char* ws = (char*)d_ws;
  unsigned short* xT   = (unsigned short*)(ws);
  unsigned short* attT = xT;                                     // alias
  unsigned short* Wqk  = (unsigned short*)(ws + 67108864);
  unsigned short* Wv   = (unsigned short*)(ws + 75497472);
  unsigned short* Wo   = (unsigned short*)(ws + 79691776);
  unsigned short* qkT  = (unsigned short*)(ws + 83886080);
  unsigned short* vbuf = (unsigned short*)(ws + 150994944);
  float*          Sbuf = (float*)(ws + 184549376);
  unsigned short* P    = (unsigned short*)(ws + 251658240);
  unsigned short* guard= (unsigned short*)(ws + 285212672);

  hipMemsetAsync(guard, 0, 4096, stream);

  transpose_x_k<<<dim3(512, 64), dim3(32, 8), 0, stream>>>(x1, xT);
  conv_w_k<<<dim3(8192), dim3(256), 0, stream>>>(wq, wk, wv, wo, Wqk, Wv, Wo);

  const int BIG = 0x40000000;
  // 1) qkT[16384][2048] = xT @ Wqk^T (+bias, q-part scaled 1/32)
  {
    GArgs a{};
    a.A = xT; a.Bt = Wqk; a.C = qkT;
    a.bias = bq; a.bias2 = bk; a.guard = guard;
    a.aBatch = 0; a.cBatch = 0;
    a.btRow0 = 0; a.btRow0Step = 0; a.btRowLim = BIG;
    a.btK0 = 0; a.btK0Step = 0; a.btKLim = BIG;
    gemm8_k<EPI_QK, 0, 2048, 2048, 2048, 2048><<<dim3(8, 64, 1), 512, 0, stream>>>(a);
  }
  // 2) v[1024][16384] = Wv @ x (+bv)
  {
    GArgs a{};
    a.A = Wv; a.Bt = xT; a.C = vbuf;
    a.bias = bv; a.guard = guard;
    a.aBatch = 0; a.cBatch = 0;
    a.btRow0 = 0; a.btRow0Step = 0; a.btRowLim = BIG;
    a.btK0 = 0; a.btK0Step = 0; a.btKLim = BIG;
    gemm8_k<EPI_V, 0, 2048, 2048, 16384, 2048><<<dim3(64, 4, 1), 512, 0, stream>>>(a);
  }
  // 3) S[n][512][1024] = Qb @ Kb^T (halo rows via guard)
  {
    GArgs a{};
    a.A = qkT; a.Bt = qkT; a.C = Sbuf;
    a.guard = guard;
    a.aBatch = 512 * 2048; a.cBatch = 512 * 1024;
    a.btRow0 = -256; a.btRow0Step = 512; a.btRowLim = 16384;
    a.btK0 = 1024; a.btK0Step = 0; a.btKLim = BIG;
    gemm8_k<EPI_S, 1, 2048, 2048, 1024, 1024><<<dim3(4, 2, 32), 512, 0, stream>>>(a);
  }
  // 4) softmax rows -> P bf16
  softmax_k<<<dim3(16384), dim3(256), 0, stream>>>(Sbuf, mask, P);
  // 5) attT[n][512][1024] = relu(P @ Vb^T) (halo cols via guard)
  {
    GArgs a{};
    a.A = P; a.Bt = vbuf; a.C = attT;
    a.guard = guard;
    a.aBatch = 512 * 1024; a.cBatch = 512 * 1024;
    a.btRow0 = 0; a.btRow0Step = 0; a.btRowLim = BIG;
    a.btK0 = -256; a.btK0Step = 512; a.btKLim = 16384;
    gemm8_k<EPI_PV, 1, 1024, 16384, 1024, 1024><<<dim3(4, 2, 32), 512, 0, stream>>>(a);
  }
  // 6) out[2048][16384] = (Wo @ attT^T + bo) * mask (fp32)
  {
    GArgs a{};
    a.A = Wo; a.Bt = attT; a.C = d_out;
    a.bias = bo; a.mask = mask; a.guard = guard;
    a.aBatch = 0; a.cBatch = 0;
    a.btRow0 = 0; a.btRow0Step = 0; a.btRowLim = BIG;
    a.btK0 = 0; a.btK0Step = 0; a.btKLim = BIG;
    gemm8_k<EPI_OUT, 0, 1024, 1024, 16384, 1024><<<dim3(64, 8, 1), 512, 0, stream>>>(a);
  }
  (void)in_sizes; (void)n_in; (void)out_size; (void)ws_size;
}

// Round 7
// 462.300 us; speedup vs baseline: 1.6418x; 1.0036x over previous
//
// AttLayer block-local attention, MI355X gfx950.
// R7: deepen staging leads. R5/R6's schedule staged b1.u3 at P0 and certified
//     it at P3 (3 phases ~ 900cyc = HBM latency) -> per-iter VM stall.
//     New schedule: stage u0,u1@P1, u2@P2, u3@P3 (mirror P5-P7); P0/P4 stage
//     nothing. Uniform 7-phase stage->consume lead. Counted VMs re-derived:
//     VM(10)@endP0/P4, VM(12)@endP1/P3/P5/P7 (each certifies >=6-phase-old
//     loads). WAR: each unit staged exactly 1 phase after last reader with
//     LGKM-certified reads + barrier in between. Reads unchanged from R5.
// Workspace: xT | Wqk | Wv | Wo | qkT | v | S | P | guard (attT aliases xT).

#include <hip/hip_runtime.h>
#include <hip/hip_bf16.h>

typedef __attribute__((ext_vector_type(4))) float f32x4;
typedef __attribute__((ext_vector_type(8))) __bf16 bf16x8;

struct ushort4_t { unsigned short x, y, z, w; };

#define DEVINL static __device__ __forceinline__

DEVINL unsigned short f2bf(float f) {  // RTNE float->bf16
  union { float f; unsigned u; } x; x.f = f;
  return (unsigned short)((x.u + 0x7FFFu + ((x.u >> 16) & 1u)) >> 16);
}

DEVINL void gload16(const void* g, void* l) {
  __builtin_amdgcn_global_load_lds((const __attribute__((address_space(1))) void*)g,
                                   (__attribute__((address_space(3))) void*)l,
                                   16, 0, 0);
}

#define SBAR()   asm volatile("s_barrier" ::: "memory")
#define LGKM0()  asm volatile("s_waitcnt lgkmcnt(0)" ::: "memory")
#define VM(n)    asm volatile("s_waitcnt vmcnt(" #n ")" ::: "memory")

// ---------------------------------------------------------------- transpose x
// x1 [2048][16384] f32 -> xT [16384][2048] bf16 (RTNE), ushort4 stores
__global__ __launch_bounds__(256) void transpose_x_k(const float* __restrict__ x,
                                                     unsigned short* __restrict__ xT) {
  __shared__ float tile[32][33];
  const int bx = blockIdx.x;  // 512
  const int by = blockIdx.y;  // 64
  const int tx = threadIdx.x; // 32
  const int ty = threadIdx.y; // 8
#pragma unroll
  for (int i = 0; i < 4; ++i) {
    int c = by * 32 + ty + i * 8;
    tile[ty + i * 8][tx] = x[(long)c * 16384 + bx * 32 + tx];
  }
  __syncthreads();
  const int t = ty * 32 + tx;
  const int lrow = t >> 3;          // 0..31 (l within tile)
  const int cq = (t & 7) << 2;      // 0..28 (channel quad)
  ushort4_t o;
  o.x = f2bf(tile[cq + 0][lrow]);
  o.y = f2bf(tile[cq + 1][lrow]);
  o.z = f2bf(tile[cq + 2][lrow]);
  o.w = f2bf(tile[cq + 3][lrow]);
  *reinterpret_cast<ushort4_t*>(xT + (long)(bx * 32 + lrow) * 2048 + by * 32 + cq) = o;
}

// ------------------------------------------------------------ weight convert
__global__ __launch_bounds__(256) void conv_w_k(const float* __restrict__ wq,
                                                const float* __restrict__ wk,
                                                const float* __restrict__ wv,
                                                const float* __restrict__ wo,
                                                unsigned short* __restrict__ Wqk,
                                                unsigned short* __restrict__ Wv,
                                                unsigned short* __restrict__ Wo) {
  long i = ((long)blockIdx.x * 256 + threadIdx.x) * 4;   // 0..8388604
  const float* src;
  unsigned short* dst;
  if (i < 4194304) {
    src = (i < 2097152) ? (wq + i) : (wk + i - 2097152);
    dst = Wqk + i;
  } else if (i < 6291456) {
    src = wv + (i - 4194304);
    dst = Wv + (i - 4194304);
  } else {
    src = wo + (i - 6291456);
    dst = Wo + (i - 6291456);
  }
  float4 v = *reinterpret_cast<const float4*>(src);
  ushort4_t o{f2bf(v.x), f2bf(v.y), f2bf(v.z), f2bf(v.w)};
  *reinterpret_cast<ushort4_t*>(dst) = o;
}

// ------------------------------------------------------------------ GEMM core
enum { EPI_QK = 0, EPI_V = 1, EPI_S = 2, EPI_PV = 3, EPI_OUT = 4 };

struct GArgs {
  const unsigned short* A;
  const unsigned short* Bt;
  void* C;
  const float* bias;
  const float* bias2;
  const float* mask;
  const unsigned short* guard;
  int aBatch, cBatch;
  int btRow0, btRow0Step, btRowLim;
  int btK0, btK0Step, btKLim;
};

// 256x256 tile, BK=64, 8 waves (2M x 4N), per-wave 128x64, 8-phase pipeline.
template <int EPI, int GUARDED, int LDA, int LDB, int LDC, int KK>
__global__ __launch_bounds__(512, 2) void gemm8_k(GArgs g) {
  constexpr int NK = KK >> 6;
  constexpr int NT = NK >> 1;
  __shared__ char lds[131072];

  const int t = threadIdx.x;
  const int l = t & 63;
  const int w = t >> 6;

  // XCD chunk swizzle (all grids % 8 == 0): each XCD gets a contiguous chunk.
  const int gx = gridDim.x, gxy = gx * gridDim.y;
  const int nwg = gxy * gridDim.z;
  int lin = blockIdx.z * gxy + blockIdx.y * gx + blockIdx.x;
  lin = (lin & 7) * (nwg >> 3) + (lin >> 3);
  const int z = lin / gxy;
  const int rres = lin - z * gxy;
  const int Mbase = (rres / gx) << 8;
  const int Nbase = (rres - (rres / gx) * gx) << 8;

  const int wr = w >> 2;
  const int wc = w & 3;
  const int fr = l & 15;
  const int fg = l >> 4;

  const unsigned short* Ab = g.A + (long)z * g.aBatch + (long)Mbase * LDA;
  const int bRowBase = g.btRow0 + z * g.btRow0Step + Nbase;
  const int bK0 = g.btK0 + z * g.btK0Step;

  const int rr = t >> 3;
  const int cb8s = t & 7;

  // stage one 16 KiB unit (2 gloads/thread) of K-tile kt into buf.
  // unit 0: A rows 0-63,128-191   unit 3: A rows 64-127,192-255
  // unit 1: B rows {0-31,64-95},{128-159,192-223}
  // unit 2: B rows {32-63,96-127},{160-191,224-255}
  auto stage = [&](int bufSel, int unit, int kt) {
    const int k0 = (kt & (NK - 1)) << 6;
    const bool isA = (unit == 0) || (unit == 3);
#pragma unroll
    for (int gph = 0; gph < 2; ++gph) {
      int row;
      if (isA) row = (unit == 0 ? 0 : 64) + (gph << 7) + rr;
      else     row = (unit == 1 ? 0 : 32) + (gph << 7) + (rr & 31) + ((rr >> 5) << 6);
      const int cbL = cb8s ^ (row & 7);
      const int gk = k0 + (cbL << 3);
      char* lp = lds + (bufSel << 16) + (isA ? 0 : 32768) + row * 128 + (cb8s << 4);
      const char* gp;
      if (isA) {
        gp = (const char*)(Ab + (long)row * LDA + gk);
      } else if (!GUARDED) {
        gp = (const char*)(g.Bt + (long)(bRowBase + row) * LDB + (bK0 + gk));
      } else {
        const int grow = bRowBase + row;
        const int gkk = bK0 + gk;
        if ((unsigned)grow < (unsigned)g.btRowLim && (unsigned)gkk < (unsigned)g.btKLim)
          gp = (const char*)(g.Bt + (long)grow * LDB + gkk);
        else
          gp = (const char*)g.guard + (l << 4);
      }
      gload16(gp, lp);
    }
  };

  const int arow = (wr << 7) + fr;
  const int brow = (wc << 6) + fr;

  auto ldA = [&](int i8, int kk, int bufSel) -> bf16x8 {
    const int row = arow + (i8 << 4);
    const int cb = ((kk << 2) | fg) ^ (row & 7);
    return *(const bf16x8*)(lds + (bufSel << 16) + row * 128 + (cb << 4));
  };
  auto ldB = [&](int j, int kk, int bufSel) -> bf16x8 {
    const int row = brow + (j << 4);
    const int cb = ((kk << 2) | fg) ^ (row & 7);
    return *(const bf16x8*)(lds + (bufSel << 16) + 32768 + row * 128 + (cb << 4));
  };

  f32x4 acc[8][4];
#pragma unroll
  for (int i = 0; i < 8; ++i)
#pragma unroll
    for (int j = 0; j < 4; ++j) acc[i][j] = f32x4{0.f, 0.f, 0.f, 0.f};

  // prologue: full steady-state issue order. b0(kt0) u0..u3, b1(kt1) u0..u3.
  stage(0, 0, 0); stage(0, 1, 0); stage(0, 2, 0); stage(0, 3, 0);
  stage(1, 0, 1); stage(1, 1, 1); stage(1, 2, 1); stage(1, 3, 1);
  VM(12);       // certify b0.u0,u1 (oldest 4); 12 stay in flight
  SBAR();

  bf16x8 fa[4][2], fb[4][2];

// kk-outer: dependent MFMAs on the same acc are spaced 8 apart.
#define MFMA_Q(QI, QJ)                                                        \
  __builtin_amdgcn_s_setprio(1);                                              \
  _Pragma("unroll") for (int kk = 0; kk < 2; ++kk)                            \
  _Pragma("unroll") for (int i = 0; i < 4; ++i)                               \
  _Pragma("unroll") for (int j = 0; j < 2; ++j)                               \
    acc[(QI)*4 + i][(QJ)*2 + j] = __builtin_amdgcn_mfma_f32_16x16x32_bf16(    \
        fa[i][kk], fb[(QJ)*2 + j][kk], acc[(QI)*4 + i][(QJ)*2 + j], 0, 0, 0); \
  __builtin_amdgcn_s_setprio(0);

#pragma unroll 1
  for (int it = 0; it < NT; ++it) {
    const int ktn0 = 2 * it + 2;
    const int ktn1 = 2 * it + 3;
    // ---- P0 (buf0, Q00): 12 reads, no stage. endVM(10) certifies b0.u2.
#pragma unroll
    for (int i = 0; i < 4; ++i) { fa[i][0] = ldA(i, 0, 0); fa[i][1] = ldA(i, 1, 0); }
#pragma unroll
    for (int j = 0; j < 2; ++j) { fb[j][0] = ldB(j, 0, 0); fb[j][1] = ldB(j, 1, 0); }
    SBAR(); LGKM0();
    MFMA_Q(0, 0);
    VM(10); SBAR();
    // ---- P1 (buf0, Q01): 4 reads, stage u0+u1. endVM(12) certifies b0.u3.
#pragma unroll
    for (int j = 2; j < 4; ++j) { fb[j][0] = ldB(j, 0, 0); fb[j][1] = ldB(j, 1, 0); }
    stage(0, 0, ktn0); stage(0, 1, ktn0);
    SBAR(); LGKM0();
    MFMA_Q(0, 1);
    VM(12); SBAR();
    // ---- P2 (buf0, Q10): 8 reads, stage u2. P3 reads nothing -> no VM.
#pragma unroll
    for (int i = 0; i < 4; ++i) { fa[i][0] = ldA(4 + i, 0, 0); fa[i][1] = ldA(4 + i, 1, 0); }
    stage(0, 2, ktn0);
    SBAR(); LGKM0();
    MFMA_Q(1, 0);
    SBAR();
    // ---- P3 (buf0, Q11): stage u3. endVM(12) certifies b1.u0,u1.
    stage(0, 3, ktn0);
    SBAR();
    MFMA_Q(1, 1);
    VM(12); SBAR();
    // ---- P4 (buf1, Q00): 12 reads, no stage. endVM(10) certifies b1.u2.
#pragma unroll
    for (int i = 0; i < 4; ++i) { fa[i][0] = ldA(i, 0, 1); fa[i][1] = ldA(i, 1, 1); }
#pragma unroll
    for (int j = 0; j < 2; ++j) { fb[j][0] = ldB(j, 0, 1); fb[j][1] = ldB(j, 1, 1); }
    SBAR(); LGKM0();
    MFMA_Q(0, 0);
    VM(10); SBAR();
    // ---- P5 (buf1, Q01): 4 reads, stage u0+u1. endVM(12) certifies b1.u3.
#pragma unroll
    for (int j = 2; j < 4; ++j) { fb[j][0] = ldB(j, 0, 1); fb[j][1] = ldB(j, 1, 1); }
    stage(1, 0, ktn1); stage(1, 1, ktn1);
    SBAR(); LGKM0();
    MFMA_Q(0, 1);
    VM(12); SBAR();
    // ---- P6 (buf1, Q10): 8 reads, stage u2. P7 reads nothing -> no VM.
#pragma unroll
    for (int i = 0; i < 4; ++i) { fa[i][0] = ldA(4 + i, 0, 1); fa[i][1] = ldA(4 + i, 1, 1); }
    stage(1, 1 + 1, ktn1);
    SBAR(); LGKM0();
    MFMA_Q(1, 0);
    SBAR();
    // ---- P7 (buf1, Q11): stage u3. endVM(12) certifies b0'.u0,u1.
    stage(1, 3, ktn1);
    SBAR();
    MFMA_Q(1, 1);
    VM(12); SBAR();
  }
  VM(0); LGKM0(); SBAR();  // drain wrapped prefetches before epilogue

  // epilogue: D row=(lane>>4)*4+r, col=lane&15 within each 16x16 fragment
#pragma unroll
  for (int ii = 0; ii < 8; ++ii)
#pragma unroll
    for (int j = 0; j < 4; ++j)
#pragma unroll
      for (int r = 0; r < 4; ++r) {
        const int row = Mbase + (wr << 7) + ii * 16 + fg * 4 + r;
        const int col = Nbase + (wc << 6) + j * 16 + fr;
        float val = acc[ii][j][r];
        const long off = (long)z * g.cBatch + (long)row * LDC + col;
        if (EPI == EPI_QK) {
          val = (col < 1024) ? (val + g.bias[col]) * 0.03125f
                             : (val + g.bias2[col - 1024]);
          ((unsigned short*)g.C)[off] = f2bf(val);
        } else if (EPI == EPI_V) {
          val += g.bias[row];
          ((unsigned short*)g.C)[off] = f2bf(val);
        } else if (EPI == EPI_S) {
          ((float*)g.C)[off] = val;
        } else if (EPI == EPI_PV) {
          val = fmaxf(val, 0.f);
          ((unsigned short*)g.C)[off] = f2bf(val);
        } else {
          val = (val + g.bias[row]) * g.mask[col];
          ((float*)g.C)[off] = val;
        }
      }
#undef MFMA_Q
}

// ------------------------------------------------------------------- softmax
__global__ __launch_bounds__(256) void softmax_k(const float* __restrict__ S,
                                                 const float* __restrict__ mask,
                                                 unsigned short* __restrict__ P) {
  const int row = blockIdx.x;      // n*512 + l
  const int n = row >> 9;
  const float* s = S + (long)row * 1024;
  unsigned short* p = P + (long)row * 1024;
  const int t = threadIdx.x;

  const float4 sv = *reinterpret_cast<const float4*>(s + t * 4);
  const int pos0 = (n << 9) + t * 4 - 256;
  float4 mv = {0.f, 0.f, 0.f, 0.f};
  if ((unsigned)pos0 < 16384u) mv = *reinterpret_cast<const float4*>(mask + pos0);
  float fm[4] = {mv.x, mv.y, mv.z, mv.w};
  if (t == 255) fm[3] = 0.f;       // m == 1023 excluded by window mask
  const float sc[4] = {sv.x, sv.y, sv.z, sv.w};

  float logit[4];
  float lmax = -3.0e38f;
#pragma unroll
  for (int k = 0; k < 4; ++k) {
    logit[k] = sc[k] + logf(fm[k] + 1e-9f);
    lmax = fmaxf(lmax, logit[k]);
  }
#pragma unroll
  for (int o = 32; o; o >>= 1) lmax = fmaxf(lmax, __shfl_xor(lmax, o, 64));
  __shared__ float red[8];
  const int wv_ = t >> 6, ln = t & 63;
  if (ln == 0) red[wv_] = lmax;
  __syncthreads();
  const float gmax = fmaxf(fmaxf(red[0], red[1]), fmaxf(red[2], red[3]));

  float e[4], lsum = 0.f;
#pragma unroll
  for (int k = 0; k < 4; ++k) { e[k] = expf(logit[k] - gmax); lsum += e[k]; }
#pragma unroll
  for (int o = 32; o; o >>= 1) lsum += __shfl_xor(lsum, o, 64);
  if (ln == 0) red[4 + wv_] = lsum;
  __syncthreads();
  const float inv = 1.f / ((red[4] + red[5]) + (red[6] + red[7]));
  ushort4_t o4;
  o4.x = f2bf(e[0] * inv * fm[0]);
  o4.y = f2bf(e[1] * inv * fm[1]);
  o4.z = f2bf(e[2] * inv * fm[2]);
  o4.w = f2bf(e[3] * inv * fm[3]);
  *reinterpret_cast<ushort4_t*>(p + t * 4) = o4;
}

// -------------------------------------------------------------------- launch
extern "C" void kernel_launch(void* const* d_in, const int* in_sizes, int n_in,
                              void* d_out, int out_size, void* d_ws, size_t ws_size,
                              hipStream_t stream) {
  const float* x1 = (const float*)d_in[0];
  const float* mask = (const float*)d_in[2];
  const float* wq = (const float*)d_in[3];
  const float* bq = (const float*)d_in[4];
  const float* wk = (const float*)d_in[5];
  const float* bk = (const float*)d_in[6];
  const float* wv = (const float*)d_in[7];
  const float* bv = (const float*)d_in[8];
  const float* wo = (const float*)d_in[9];
  const float* bo = (const float*)d_in[10];

  char* ws = (char*)d_ws;
  unsigned short* xT   = (unsigned short*)(ws);
  unsigned short* attT = xT;                                     // alias
  unsigned short* Wqk  = (unsigned short*)(ws + 67108864);
  unsigned short* Wv   = (unsigned short*)(ws + 75497472);
  unsigned short* Wo   = (unsigned short*)(ws + 79691776);
  unsigned short* qkT  = (unsigned short*)(ws + 83886080);
  unsigned short* vbuf = (unsigned short*)(ws + 150994944);
  float*          Sbuf = (float*)(ws + 184549376);
  unsigned short* P    = (unsigned short*)(ws + 251658240);
  unsigned short* guard= (unsigned short*)(ws + 285212672);

  hipMemsetAsync(guard, 0, 4096, stream);

  transpose_x_k<<<dim3(512, 64), dim3(32, 8), 0, stream>>>(x1, xT);
  conv_w_k<<<dim3(8192), dim3(256), 0, stream>>>(wq, wk, wv, wo, Wqk, Wv, Wo);

  const int BIG = 0x40000000;
  // 1) qkT[16384][2048] = xT @ Wqk^T (+bias, q-part scaled 1/32)
  {
    GArgs a{};
    a.A = xT; a.Bt = Wqk; a.C = qkT;
    a.bias = bq; a.bias2 = bk; a.guard = guard;
    a.aBatch = 0; a.cBatch = 0;
    a.btRow0 = 0; a.btRow0Step = 0; a.btRowLim = BIG;
    a.btK0 = 0; a.btK0Step = 0; a.btKLim = BIG;
    gemm8_k<EPI_QK, 0, 2048, 2048, 2048, 2048><<<dim3(8, 64, 1), 512, 0, stream>>>(a);
  }
  // 2) v[1024][16384] = Wv @ x (+bv)
  {
    GArgs a{};
    a.A = Wv; a.Bt = xT; a.C = vbuf;
    a.bias = bv; a.guard = guard;
    a.aBatch = 0; a.cBatch = 0;
    a.btRow0 = 0; a.btRow0Step = 0; a.btRowLim = BIG;
    a.btK0 = 0; a.btK0Step = 0; a.btKLim = BIG;
    gemm8_k<EPI_V, 0, 2048, 2048, 16384, 2048><<<dim3(64, 4, 1), 512, 0, stream>>>(a);
  }
  // 3) S[n][512][1024] = Qb @ Kb^T (halo rows via guard)
  {
    GArgs a{};
    a.A = qkT; a.Bt = qkT; a.C = Sbuf;
    a.guard = guard;
    a.aBatch = 512 * 2048; a.cBatch = 512 * 1024;
    a.btRow0 = -256; a.btRow0Step = 512; a.btRowLim = 16384;
    a.btK0 = 1024; a.btK0Step = 0; a.btKLim = BIG;
    gemm8_k<EPI_S, 1, 2048, 2048, 1024, 1024><<<dim3(4, 2, 32), 512, 0, stream>>>(a);
  }
  // 4) softmax rows -> P bf16
  softmax_k<<<dim3(16384), dim3(256), 0, stream>>>(Sbuf, mask, P);
  // 5) attT[n][512][1024] = relu(P @ Vb^T) (halo cols via guard)
  {
    GArgs a{};
    a.A = P; a.Bt = vbuf; a.C = attT;
    a.guard = guard;
    a.aBatch = 512 * 1024; a.cBatch = 512 * 1024;
    a.btRow0 = 0; a.btRow0Step = 0; a.btRowLim = BIG;
    a.btK0 = -256; a.btK0Step = 512; a.btKLim = 16384;
    gemm8_k<EPI_PV, 1, 1024, 16384, 1024, 1024><<<dim3(4, 2, 32), 512, 0, stream>>>(a);
  }
  // 6) out[2048][16384] = (Wo @ attT^T + bo) * mask (fp32)
  {
    GArgs a{};
    a.A = Wo; a.Bt = attT; a.C = d_out;
    a.bias = bo; a.mask = mask; a.guard = guard;
    a.aBatch = 0; a.cBatch = 0;
    a.btRow0 = 0; a.btRow0Step = 0; a.btRowLim = BIG;
    a.btK0 = 0; a.btK0Step = 0; a.btKLim = BIG;
    gemm8_k<EPI_OUT, 0, 1024, 1024, 16384, 1024><<<dim3(64, 8, 1), 512, 0, stream>>>(a);
  }
  (void)in_sizes; (void)n_in; (void)out_size; (void)ws_size;
}